// Round 1
// baseline (384.793 us; speedup 1.0000x reference)
//
#include <hip/hip_runtime.h>
#include <hip/hip_fp16.h>

typedef _Float16 half8 __attribute__((ext_vector_type(8)));
typedef float f32x16 __attribute__((ext_vector_type(16)));

#define MFMA16(A, B, C) __builtin_amdgcn_mfma_f32_32x32x16_f16((A), (B), (C), 0, 0, 0)

__device__ __forceinline__ f32x16 fzero16() {
  f32x16 z;
#pragma unroll
  for (int i = 0; i < 16; ++i) z[i] = 0.0f;
  return z;
}

// ---------------------------------------------------------------------------
// Kernel 1: 1x1-conv projections (fp32 exact) + pack q/k/v into MFMA fragment
// layout (fp16).
//   q/k packed:  [b][rt=n/32][ds=d/16][l=64][j=8]   (B-operand / A-operand frags)
//   v packed:    [b][ms=m/16][u=c/32][l=64][j=8]    (A-operand frags)
// k-permutation kmap16(h,j) = 4h + (j&3) + 8*(j>>2), h = lane>>5.
// ---------------------------------------------------------------------------
__global__ __launch_bounds__(256) void proj_pack_kernel(
    const float* __restrict__ x,
    const float* __restrict__ w1, const float* __restrict__ b1,
    const float* __restrict__ w2, const float* __restrict__ b2,
    const float* __restrict__ w3, const float* __restrict__ b3,
    _Float16* __restrict__ qb, _Float16* __restrict__ kb, _Float16* __restrict__ vb)
{
  __shared__ float xs[256][64];   // [c][n], 64 KB
  const int t = threadIdx.x;
  const int b = blockIdx.x >> 6;
  const int nt = blockIdx.x & 63;
  const int n0 = nt * 64;
  const float* xb = x + (size_t)b * 256 * 4096;

#pragma unroll 4
  for (int it = 0; it < 64; ++it) {
    const int c = it * 4 + (t >> 6);
    xs[c][t & 63] = xb[(size_t)c * 4096 + n0 + (t & 63)];
  }
  __syncthreads();

  const int n = t & 63;
  const int stripe = t >> 6;      // wave-uniform
  const int n_abs = n0 + n;

  // ---- q & k (8 outputs each per thread) ----
  float accq[8], acck[8];
#pragma unroll
  for (int i = 0; i < 8; ++i) { accq[i] = 0.f; acck[i] = 0.f; }
  for (int chv = 0; chv < 4; ++chv) {
    float xr[64];
#pragma unroll
    for (int cc = 0; cc < 64; ++cc) xr[cc] = xs[chv * 64 + cc][n];
#pragma unroll
    for (int o = 0; o < 8; ++o) {
      const int d = stripe * 8 + o;
      const float* w1r = w1 + d * 256 + chv * 64;
      const float* w2r = w2 + d * 256 + chv * 64;
      float a0 = 0.f, a1 = 0.f;
#pragma unroll
      for (int cc = 0; cc < 64; ++cc) { a0 += w1r[cc] * xr[cc]; a1 += w2r[cc] * xr[cc]; }
      accq[o] += a0; acck[o] += a1;
    }
  }
  {
    const int rt = n_abs >> 5;
    const int lbase = n_abs & 31;
#pragma unroll
    for (int o = 0; o < 8; ++o) {
      const int d = stripe * 8 + o;
      const float qv = accq[o] + b1[d];
      const float kv = acck[o] + b2[d];
      const int drel = d & 15;
      const int ds = d >> 4;
      const int hh = (drel & 7) >> 2;
      const int jj = (drel & 3) + 4 * (drel >> 3);
      const size_t base = ((((size_t)b * 128 + rt) * 2 + ds) * 64 + (lbase + 32 * hh)) * 8 + jj;
      qb[base] = (_Float16)qv;
      kb[base] = (_Float16)kv;
    }
  }

  // ---- v (64 outputs per thread, 4 passes of 16) ----
  const int ms = n_abs >> 4;
  const int mrel = n_abs & 15;
  const int vhh = (mrel & 7) >> 2;
  const int vjj = (mrel & 3) + 4 * (mrel >> 3);
  for (int grp = 0; grp < 4; ++grp) {
    float vacc[16];
#pragma unroll
    for (int i = 0; i < 16; ++i) vacc[i] = 0.f;
    for (int chv = 0; chv < 4; ++chv) {
      float xr[64];
#pragma unroll
      for (int cc = 0; cc < 64; ++cc) xr[cc] = xs[chv * 64 + cc][n];
#pragma unroll
      for (int o = 0; o < 16; ++o) {
        const int co = stripe * 64 + grp * 16 + o;
        const float* w3r = w3 + co * 256 + chv * 64;
        float a = 0.f;
#pragma unroll
        for (int cc = 0; cc < 64; ++cc) a += w3r[cc] * xr[cc];
        vacc[o] += a;
      }
    }
#pragma unroll
    for (int o = 0; o < 16; ++o) {
      const int co = stripe * 64 + grp * 16 + o;
      const float vv = vacc[o] + b3[co];
      const size_t vi = ((((size_t)b * 256 + ms) * 8 + (co >> 5)) * 64 + ((co & 31) + 32 * vhh)) * 8 + vjj;
      vb[vi] = (_Float16)vv;
    }
  }
}

// ---------------------------------------------------------------------------
// Kernel 2: phase A — row max M[b][r] of energy. Bitwise-identical mfma
// sequence to phase B so exp(S - M) <= 1 exactly.
// ---------------------------------------------------------------------------
__global__ __launch_bounds__(64) void rowmax_kernel(
    const _Float16* __restrict__ qb, const _Float16* __restrict__ kb,
    float* __restrict__ Mrow)
{
  const int b = blockIdx.x >> 7;
  const int sl = blockIdx.x & 127;   // 32-row slab
  const int l = threadIdx.x;
  const _Float16* qp = qb + ((((size_t)b * 128 + sl) * 2) * 64 + l) * 8;
  const half8 q0 = *(const half8*)qp;
  const half8 q1 = *(const half8*)(qp + 64 * 8);
  float vm = -3.0e38f;
#pragma unroll 2
  for (int mt = 0; mt < 128; ++mt) {
    const _Float16* kp = kb + ((((size_t)b * 128 + mt) * 2) * 64 + l) * 8;
    const half8 k0 = *(const half8*)kp;
    const half8 k1 = *(const half8*)(kp + 64 * 8);
    f32x16 s = fzero16();
    s = MFMA16(k0, q0, s);
    s = MFMA16(k1, q1, s);
#pragma unroll
    for (int i = 0; i < 16; ++i) vm = fmaxf(vm, s[i]);
  }
  vm = fmaxf(vm, __shfl_xor(vm, 32));
  if (l < 32) Mrow[(size_t)b * 4096 + sl * 32 + l] = vm;
}

// ---------------------------------------------------------------------------
// Kernel 3: phase B — fused S^T = K·Q^T, P = exp(S-M) (in-register),
// O^T = V·P^T, normalize by locally-accumulated L, add residual.
// Block: 256 thr / 4 waves; wave owns 64 q-rows (2 slabs of 32);
// block covers r-tile 256 x cout-chunk 64. Grid = 4b x 16rt x 4ch = 256.
// ---------------------------------------------------------------------------
__global__ __launch_bounds__(256) void attn_kernel(
    const _Float16* __restrict__ qb, const _Float16* __restrict__ kb,
    const _Float16* __restrict__ vb, const float* __restrict__ Mrow,
    const float* __restrict__ x, float* __restrict__ out)
{
  __shared__ __align__(16) _Float16 lds[768 * 8];  // V: [0,4096) halves, K: [4096,6144)
  const int t = threadIdx.x;
  const int w = t >> 6;
  const int l = t & 63;
  const int lr = l & 31;
  const int hh = l >> 5;
  const int bid = blockIdx.x;
  const int ch = bid & 3;
  const int rt = (bid >> 2) & 15;
  const int b = bid >> 6;

  half8 qf[2][2];
  float Mr[2], Lacc[2];
  f32x16 acc[2][2];
#pragma unroll
  for (int s2 = 0; s2 < 2; ++s2) {
    const int rt32 = rt * 8 + w * 2 + s2;
    const _Float16* qp = qb + (((size_t)b * 128 + rt32) * 2 * 64 + l) * 8;
    qf[s2][0] = *(const half8*)qp;
    qf[s2][1] = *(const half8*)(qp + 64 * 8);
    Mr[s2] = Mrow[(size_t)b * 4096 + rt32 * 32 + lr];
    Lacc[s2] = 0.f;
    acc[s2][0] = fzero16();
    acc[s2][1] = fzero16();
  }

  for (int t64 = 0; t64 < 64; ++t64) {
    // ---- stage V (8 KB: 8 sub-blocks) + K (4 KB: 4 sub-blocks) ----
#pragma unroll
    for (int i = 0; i < 3; ++i) {
      const int idx = t + 256 * i;     // 0..767, 16 B each
      const int sb = idx >> 6;
      const int li = idx & 63;
      const _Float16* src;
      if (sb < 8) {
        const int ks = sb >> 1, ul = sb & 1;
        src = vb + ((((size_t)b * 256 + (t64 * 4 + ks)) * 8 + (ch * 2 + ul)) * 64 + li) * 8;
      } else {
        const int sbk = sb - 8;
        const int ms2 = sbk >> 1, ds = sbk & 1;
        src = kb + ((((size_t)b * 128 + (t64 * 2 + ms2)) * 2 + ds) * 64 + li) * 8;
      }
      *(uint4*)&lds[idx * 8] = *(const uint4*)src;
    }
    __syncthreads();

    // ---- K frags ----
    half8 kf[2][2];
#pragma unroll
    for (int ms2 = 0; ms2 < 2; ++ms2)
#pragma unroll
      for (int ds = 0; ds < 2; ++ds)
        kf[ms2][ds] = *(const half8*)&lds[(512 + (ms2 * 2 + ds) * 64 + l) * 8];

    // ---- S^T = K · Q^T (both slabs; same op order as rowmax_kernel) ----
    f32x16 s[2][2];
#pragma unroll
    for (int s2 = 0; s2 < 2; ++s2)
#pragma unroll
      for (int ms2 = 0; ms2 < 2; ++ms2) {
        f32x16 sv = fzero16();
        sv = MFMA16(kf[ms2][0], qf[s2][0], sv);
        sv = MFMA16(kf[ms2][1], qf[s2][1], sv);
        s[s2][ms2] = sv;
      }

    // ---- P = exp(S - M): in-register, pack B-frags (pb[s2][ks][j] = p[ks>>1][j+8*(ks&1)]) ----
    half8 pb[2][4];
#pragma unroll
    for (int s2 = 0; s2 < 2; ++s2) {
      float lsum = 0.f;
#pragma unroll
      for (int ms2 = 0; ms2 < 2; ++ms2)
#pragma unroll
        for (int kh = 0; kh < 2; ++kh) {
          half8 ph;
#pragma unroll
          for (int j = 0; j < 8; ++j) {
            const float pv = __expf(s[s2][ms2][j + 8 * kh] - Mr[s2]);
            lsum += pv;
            ph[j] = (_Float16)pv;
          }
          pb[s2][ms2 * 2 + kh] = ph;
        }
      Lacc[s2] += lsum;
    }

    // ---- O^T += V · P^T (each V frag reused for both slabs) ----
#pragma unroll
    for (int ks = 0; ks < 4; ++ks)
#pragma unroll
      for (int ul = 0; ul < 2; ++ul) {
        const half8 vf = *(const half8*)&lds[((ks * 2 + ul) * 64 + l) * 8];
#pragma unroll
        for (int s2 = 0; s2 < 2; ++s2)
          acc[s2][ul] = MFMA16(vf, pb[s2][ks], acc[s2][ul]);
      }
    __syncthreads();
  }

  // ---- epilogue: normalize + residual ----
#pragma unroll
  for (int s2 = 0; s2 < 2; ++s2) {
    const float Lt = Lacc[s2] + __shfl_xor(Lacc[s2], 32);
    const float inv = 1.0f / Lt;
    const int nn = rt * 256 + w * 64 + s2 * 32 + lr;
#pragma unroll
    for (int ul = 0; ul < 2; ++ul)
#pragma unroll
      for (int reg = 0; reg < 16; ++reg) {
        const int crel = (reg & 3) + 8 * (reg >> 2) + 4 * hh;
        const int cout = ch * 64 + ul * 32 + crel;
        const size_t oi = ((size_t)b * 256 + cout) * 4096 + nn;
        out[oi] = acc[s2][ul][reg] * inv + x[oi];
      }
  }
}

extern "C" void kernel_launch(void* const* d_in, const int* in_sizes, int n_in,
                              void* d_out, int out_size, void* d_ws, size_t ws_size,
                              hipStream_t stream) {
  const float* x  = (const float*)d_in[0];
  const float* w1 = (const float*)d_in[1];
  const float* b1 = (const float*)d_in[2];
  const float* w2 = (const float*)d_in[3];
  const float* b2 = (const float*)d_in[4];
  const float* w3 = (const float*)d_in[5];
  const float* b3 = (const float*)d_in[6];
  float* out = (float*)d_out;

  // workspace layout (10.1 MB total)
  _Float16* qb = (_Float16*)d_ws;                          // 1 MB
  _Float16* kb = (_Float16*)((char*)d_ws + (1u << 20));    // 1 MB
  _Float16* vb = (_Float16*)((char*)d_ws + (2u << 20));    // 8 MB
  float* Mrow  = (float*)((char*)d_ws + (10u << 20));      // 64 KB

  hipLaunchKernelGGL(proj_pack_kernel, dim3(256), dim3(256), 0, stream,
                     x, w1, b1, w2, b2, w3, b3, qb, kb, vb);
  hipLaunchKernelGGL(rowmax_kernel, dim3(512), dim3(64), 0, stream, qb, kb, Mrow);
  hipLaunchKernelGGL(attn_kernel, dim3(256), dim3(256), 0, stream,
                     qb, kb, vb, Mrow, x, out);
}

// Round 3
// 206.864 us; speedup vs baseline: 1.8601x; 1.8601x over previous
//
#include <hip/hip_runtime.h>
#include <hip/hip_fp16.h>

typedef _Float16 half8 __attribute__((ext_vector_type(8)));
typedef float f32x16 __attribute__((ext_vector_type(16)));

#define MFMA16(A, B, C) __builtin_amdgcn_mfma_f32_32x32x16_f16((A), (B), (C), 0, 0, 0)

__device__ __forceinline__ f32x16 fzero16() {
  f32x16 z;
#pragma unroll
  for (int i = 0; i < 16; ++i) z[i] = 0.0f;
  return z;
}

struct HiLo { _Float16 hi, lo; };
__device__ __forceinline__ HiLo split1(float f) {
  HiLo r;
  r.hi = (_Float16)f;
  r.lo = (_Float16)(f - (float)r.hi);
  return r;
}

// ---------------------------------------------------------------------------
// q/k projection: [64 dout] x [N] = W_qk * x, fp16 MFMA with hi/lo split.
// Output packed frag layout [b][rt][ds][l][j]; acc reg r -> ds=r>>3, j order
// matches slot order, so stores are contiguous half8.
// Grid: 4b x 32; block 256 (4 waves, wave = one 32-row n-tile).
// ---------------------------------------------------------------------------
__global__ __launch_bounds__(256) void qk_proj_kernel(
    const float* __restrict__ x,
    const float* __restrict__ w1, const float* __restrict__ b1,
    const float* __restrict__ w2, const float* __restrict__ b2,
    _Float16* __restrict__ qb, _Float16* __restrict__ kb)
{
  const int t = threadIdx.x, w = t >> 6, l = t & 63;
  const int lr = l & 31, h = l >> 5;
  const int b = blockIdx.x >> 5;
  const int rt = (blockIdx.x & 31) * 4 + w;          // [0,128)
  const float* xb = x + (size_t)b * 256 * 4096 + rt * 32 + lr;

  f32x16 accq = fzero16(), acck = fzero16();

  for (int cs = 0; cs < 16; ++cs) {
    const int c0 = cs * 16 + 4 * h;
    half8 xh, xl;
#pragma unroll
    for (int j = 0; j < 8; ++j) {
      const int c = c0 + (j & 3) + 8 * (j >> 2);
      const HiLo s = split1(xb[(size_t)c * 4096]);
      xh[j] = s.hi; xl[j] = s.lo;
    }
    half8 w1h, w1l, w2h, w2l;
    const float* p1 = w1 + lr * 256 + c0;
    const float* p2 = w2 + lr * 256 + c0;
#pragma unroll
    for (int j = 0; j < 8; ++j) {
      const int c = (j & 3) + 8 * (j >> 2);
      const HiLo s1 = split1(p1[c]);
      const HiLo s2 = split1(p2[c]);
      w1h[j] = s1.hi; w1l[j] = s1.lo;
      w2h[j] = s2.hi; w2l[j] = s2.lo;
    }
    accq = MFMA16(w1h, xh, accq);
    accq = MFMA16(w1h, xl, accq);
    accq = MFMA16(w1l, xh, accq);
    acck = MFMA16(w2h, xh, acck);
    acck = MFMA16(w2h, xl, acck);
    acck = MFMA16(w2l, xh, acck);
  }

#pragma unroll
  for (int ds = 0; ds < 2; ++ds) {
    half8 phq, phk;
#pragma unroll
    for (int j = 0; j < 8; ++j) {
      const int d = 16 * ds + 4 * h + (j & 3) + 8 * (j >> 2);
      phq[j] = (_Float16)(accq[8 * ds + j] + b1[d]);
      phk[j] = (_Float16)(acck[8 * ds + j] + b2[d]);
    }
    const size_t o = ((((size_t)b * 128 + rt) * 2 + ds) * 64 + l) * 8;
    *(half8*)&qb[o] = phq;
    *(half8*)&kb[o] = phk;
  }
}

// ---------------------------------------------------------------------------
// v projection: v^T = x^T * w3^T  ([N n-rows] x [256 co-cols]), so the MFMA
// output register dim is m(=n) and lane dim is co — exactly V's A-fragment
// layout. Grid: 4b x 128 (one 32-row n-tile per block); wave w -> co-tiles
// {2w, 2w+1}.
// ---------------------------------------------------------------------------
__global__ __launch_bounds__(256) void v_proj_kernel(
    const float* __restrict__ x, const float* __restrict__ w3,
    const float* __restrict__ b3, _Float16* __restrict__ vb)
{
  const int t = threadIdx.x, w = t >> 6, l = t & 63;
  const int lr = l & 31, h = l >> 5;
  const int b = blockIdx.x >> 7;
  const int nt = blockIdx.x & 127;
  const float* xb = x + (size_t)b * 256 * 4096 + nt * 32 + lr;
  const int cot0 = w * 2, cot1 = w * 2 + 1;

  f32x16 acc0 = fzero16(), acc1 = fzero16();

  for (int cs = 0; cs < 16; ++cs) {
    const int c0 = cs * 16 + 4 * h;
    half8 xh, xl;
#pragma unroll
    for (int j = 0; j < 8; ++j) {
      const int c = c0 + (j & 3) + 8 * (j >> 2);
      const HiLo s = split1(xb[(size_t)c * 4096]);
      xh[j] = s.hi; xl[j] = s.lo;
    }
    half8 wh0, wl0, wh1, wl1;
    const float* q0 = w3 + (size_t)(cot0 * 32 + lr) * 256 + c0;
    const float* q1 = w3 + (size_t)(cot1 * 32 + lr) * 256 + c0;
#pragma unroll
    for (int j = 0; j < 8; ++j) {
      const int c = (j & 3) + 8 * (j >> 2);
      const HiLo s0 = split1(q0[c]);
      const HiLo s1 = split1(q1[c]);
      wh0[j] = s0.hi; wl0[j] = s0.lo;
      wh1[j] = s1.hi; wl1[j] = s1.lo;
    }
    acc0 = MFMA16(xh, wh0, acc0);
    acc0 = MFMA16(xl, wh0, acc0);
    acc0 = MFMA16(xh, wl0, acc0);
    acc1 = MFMA16(xh, wh1, acc1);
    acc1 = MFMA16(xl, wh1, acc1);
    acc1 = MFMA16(xh, wl1, acc1);
  }

  const float bv0 = b3[cot0 * 32 + lr];
  const float bv1 = b3[cot1 * 32 + lr];
#pragma unroll
  for (int hf = 0; hf < 2; ++hf) {
    half8 p0, p1;
#pragma unroll
    for (int j = 0; j < 8; ++j) {
      p0[j] = (_Float16)(acc0[8 * hf + j] + bv0);
      p1[j] = (_Float16)(acc1[8 * hf + j] + bv1);
    }
    const int ms = nt * 2 + hf;
    *(half8*)&vb[((((size_t)b * 256 + ms) * 8 + cot0) * 64 + l) * 8] = p0;
    *(half8*)&vb[((((size_t)b * 256 + ms) * 8 + cot1) * 64 + l) * 8] = p1;
  }
}

// ---------------------------------------------------------------------------
// rowmax: 4 waves/block, wave w covers m-tiles [32w, 32w+32); LDS max-reduce.
// Same MFMA op order as attn's QK so M is (near-)exact row max.
// ---------------------------------------------------------------------------
__global__ __launch_bounds__(256) void rowmax_kernel(
    const _Float16* __restrict__ qb, const _Float16* __restrict__ kb,
    float* __restrict__ Mrow)
{
  __shared__ float red[4][32];
  const int t = threadIdx.x, w = t >> 6, l = t & 63;
  const int b = blockIdx.x >> 7;
  const int sl = blockIdx.x & 127;
  const _Float16* qp = qb + ((((size_t)b * 128 + sl) * 2) * 64 + l) * 8;
  const half8 q0 = *(const half8*)qp;
  const half8 q1 = *(const half8*)(qp + 512);
  float vm = -3.0e38f;
  for (int mt = w * 32; mt < w * 32 + 32; ++mt) {
    const _Float16* kp = kb + ((((size_t)b * 128 + mt) * 2) * 64 + l) * 8;
    const half8 k0 = *(const half8*)kp;
    const half8 k1 = *(const half8*)(kp + 512);
    f32x16 s = fzero16();
    s = MFMA16(k0, q0, s);
    s = MFMA16(k1, q1, s);
#pragma unroll
    for (int i = 0; i < 16; ++i) vm = fmaxf(vm, s[i]);
  }
  vm = fmaxf(vm, __shfl_xor(vm, 32));
  if (l < 32) red[w][l] = vm;
  __syncthreads();
  if (t < 32) {
    float m = fmaxf(fmaxf(red[0][t], red[1][t]), fmaxf(red[2][t], red[3][t]));
    Mrow[(size_t)b * 4096 + sl * 32 + t] = m;
  }
}

// ---------------------------------------------------------------------------
// attn: fused S^T = K*Q^T, P = exp(S-M), O^T = V*P^T, normalize, residual.
// cout split 8 ways (32 couts/block) -> grid 512 = 2 blocks/CU for latency
// hiding. Wave owns 64 q-rows (2 slabs); LDS/iter: V 4KB + K 4KB.
// ---------------------------------------------------------------------------
__global__ __launch_bounds__(256) void attn_kernel(
    const _Float16* __restrict__ qb, const _Float16* __restrict__ kb,
    const _Float16* __restrict__ vb, const float* __restrict__ Mrow,
    const float* __restrict__ x, float* __restrict__ out)
{
  __shared__ __align__(16) _Float16 lds[512 * 8];  // V: sb 0-3, K: sb 4-7
  const int t = threadIdx.x, w = t >> 6, l = t & 63;
  const int lr = l & 31, hh = l >> 5;
  const int bid = blockIdx.x;
  const int ch = bid & 7;
  const int rt = (bid >> 3) & 15;
  const int b = bid >> 7;

  half8 qf[2][2];
  float Mr[2], Lacc[2];
  f32x16 acc[2];
#pragma unroll
  for (int s2 = 0; s2 < 2; ++s2) {
    const int rt32 = rt * 8 + w * 2 + s2;
    const _Float16* qp = qb + (((size_t)b * 128 + rt32) * 2 * 64 + l) * 8;
    qf[s2][0] = *(const half8*)qp;
    qf[s2][1] = *(const half8*)(qp + 512);
    Mr[s2] = Mrow[(size_t)b * 4096 + rt32 * 32 + lr];
    Lacc[s2] = 0.f;
    acc[s2] = fzero16();
  }

  for (int t64 = 0; t64 < 64; ++t64) {
#pragma unroll
    for (int i = 0; i < 2; ++i) {
      const int idx = t + 256 * i;   // 0..511, 16 B each
      const int sb = idx >> 6;
      const int li = idx & 63;
      const _Float16* src;
      if (sb < 4) {
        src = vb + ((((size_t)b * 256 + (t64 * 4 + sb)) * 8 + ch) * 64 + li) * 8;
      } else {
        const int sbk = sb - 4;
        src = kb + ((((size_t)b * 128 + (t64 * 2 + (sbk >> 1))) * 2 + (sbk & 1)) * 64 + li) * 8;
      }
      *(uint4*)&lds[idx * 8] = *(const uint4*)src;
    }
    __syncthreads();

    half8 kf[2][2];
#pragma unroll
    for (int ms2 = 0; ms2 < 2; ++ms2)
#pragma unroll
      for (int ds = 0; ds < 2; ++ds)
        kf[ms2][ds] = *(const half8*)&lds[((4 + ms2 * 2 + ds) * 64 + l) * 8];

    f32x16 s[2][2];
#pragma unroll
    for (int s2 = 0; s2 < 2; ++s2)
#pragma unroll
      for (int ms2 = 0; ms2 < 2; ++ms2) {
        f32x16 sv = fzero16();
        sv = MFMA16(kf[ms2][0], qf[s2][0], sv);
        sv = MFMA16(kf[ms2][1], qf[s2][1], sv);
        s[s2][ms2] = sv;
      }

    half8 pb[2][4];
#pragma unroll
    for (int s2 = 0; s2 < 2; ++s2) {
      float lsum = 0.f;
#pragma unroll
      for (int ms2 = 0; ms2 < 2; ++ms2)
#pragma unroll
        for (int kh = 0; kh < 2; ++kh) {
          half8 ph;
#pragma unroll
          for (int j = 0; j < 8; ++j) {
            const float pv = __expf(s[s2][ms2][j + 8 * kh] - Mr[s2]);
            lsum += pv;
            ph[j] = (_Float16)pv;
          }
          pb[s2][ms2 * 2 + kh] = ph;
        }
      Lacc[s2] += lsum;
    }

#pragma unroll
    for (int ks = 0; ks < 4; ++ks) {
      const half8 vf = *(const half8*)&lds[(ks * 64 + l) * 8];
#pragma unroll
      for (int s2 = 0; s2 < 2; ++s2)
        acc[s2] = MFMA16(vf, pb[s2][ks], acc[s2]);
    }
    __syncthreads();
  }

#pragma unroll
  for (int s2 = 0; s2 < 2; ++s2) {
    const float Lt = Lacc[s2] + __shfl_xor(Lacc[s2], 32);
    const float inv = 1.0f / Lt;
    const int nn = rt * 256 + w * 64 + s2 * 32 + lr;
#pragma unroll
    for (int reg = 0; reg < 16; ++reg) {
      const int crel = (reg & 3) + 8 * (reg >> 2) + 4 * hh;
      const int cout = ch * 32 + crel;
      const size_t oi = ((size_t)b * 256 + cout) * 4096 + nn;
      out[oi] = acc[s2][reg] * inv + x[oi];
    }
  }
}

extern "C" void kernel_launch(void* const* d_in, const int* in_sizes, int n_in,
                              void* d_out, int out_size, void* d_ws, size_t ws_size,
                              hipStream_t stream) {
  const float* x  = (const float*)d_in[0];
  const float* w1 = (const float*)d_in[1];
  const float* b1 = (const float*)d_in[2];
  const float* w2 = (const float*)d_in[3];
  const float* b2 = (const float*)d_in[4];
  const float* w3 = (const float*)d_in[5];
  const float* b3 = (const float*)d_in[6];
  float* out = (float*)d_out;

  _Float16* qb = (_Float16*)d_ws;                          // 1 MB
  _Float16* kb = (_Float16*)((char*)d_ws + (1u << 20));    // 1 MB
  _Float16* vb = (_Float16*)((char*)d_ws + (2u << 20));    // 8 MB
  float* Mrow  = (float*)((char*)d_ws + (10u << 20));      // 64 KB

  hipLaunchKernelGGL(qk_proj_kernel, dim3(128), dim3(256), 0, stream,
                     x, w1, b1, w2, b2, qb, kb);
  hipLaunchKernelGGL(v_proj_kernel, dim3(512), dim3(256), 0, stream,
                     x, w3, b3, vb);
  hipLaunchKernelGGL(rowmax_kernel, dim3(512), dim3(256), 0, stream, qb, kb, Mrow);
  hipLaunchKernelGGL(attn_kernel, dim3(512), dim3(256), 0, stream,
                     qb, kb, vb, Mrow, x, out);
}

// Round 4
// 157.143 us; speedup vs baseline: 2.4487x; 1.3164x over previous
//
#include <hip/hip_runtime.h>
#include <hip/hip_fp16.h>

typedef _Float16 half8 __attribute__((ext_vector_type(8)));
typedef _Float16 half2v __attribute__((ext_vector_type(2)));
typedef float f32x16 __attribute__((ext_vector_type(16)));
typedef float f32x4v __attribute__((ext_vector_type(4)));

#define MFMA16(A, B, C) __builtin_amdgcn_mfma_f32_32x32x16_f16((A), (B), (C), 0, 0, 0)

#define GLDS16(gsrc, ldst)                                                     \
  __builtin_amdgcn_global_load_lds(                                            \
      (const __attribute__((address_space(1))) unsigned int*)(gsrc),           \
      (__attribute__((address_space(3))) unsigned int*)(ldst), 16, 0, 0)

__device__ __forceinline__ f32x16 fzero16() {
  f32x16 z;
#pragma unroll
  for (int i = 0; i < 16; ++i) z[i] = 0.0f;
  return z;
}

struct HiLo { _Float16 hi, lo; };
__device__ __forceinline__ HiLo split1(float f) {
  HiLo r;
  r.hi = (_Float16)f;
  r.lo = (_Float16)(f - (float)r.hi);
  return r;
}

// ---------------------------------------------------------------------------
// wprep: pre-split weights into hi/lo fp16 MFMA-fragment layout.
// w1p/w2p: [hl][cs][l][j]   (hi at 0, lo at +8192 halves)   32 KB each
// w3p:     [hl][cot][cs][l][j] (hi at 0, lo at +65536)      256 KB
// col map: col = cs*16 + 4h + (j&3) + 8*(j>>2), h = l>>5.
// ---------------------------------------------------------------------------
__global__ __launch_bounds__(256) void wprep_kernel(
    const float* __restrict__ w1, const float* __restrict__ w2,
    const float* __restrict__ w3,
    _Float16* __restrict__ w1p, _Float16* __restrict__ w2p,
    _Float16* __restrict__ w3p)
{
  const int t = threadIdx.x;
  const int blk = blockIdx.x;
  if (blk < 8) {
    const int cot = blk;
    for (int e = t; e < 8192; e += 256) {
      const int j = e & 7, l = (e >> 3) & 63, cs = e >> 9;
      const int lr = l & 31, h = l >> 5;
      const int row = cot * 32 + lr;
      const int col = cs * 16 + 4 * h + (j & 3) + 8 * (j >> 2);
      const HiLo s = split1(w3[row * 256 + col]);
      const int idx = ((cot * 16 + cs) * 64 + l) * 8 + j;
      w3p[idx] = s.hi;
      w3p[65536 + idx] = s.lo;
    }
  } else {
    for (int e = t; e < 8192; e += 256) {
      const int j = e & 7, l = (e >> 3) & 63, cs = e >> 9;
      const int lr = l & 31, h = l >> 5;
      const int col = cs * 16 + 4 * h + (j & 3) + 8 * (j >> 2);
      const HiLo s1 = split1(w1[lr * 256 + col]);
      const HiLo s2 = split1(w2[lr * 256 + col]);
      const int idx = (cs * 64 + l) * 8 + j;
      w1p[idx] = s1.hi; w1p[8192 + idx] = s1.lo;
      w2p[idx] = s2.hi; w2p[8192 + idx] = s2.lo;
    }
  }
}

// ---------------------------------------------------------------------------
// q/k projection with pre-split weights; 2-way K-split + LDS reduce.
// Grid 4b x 64; block 256. Wave pair p=w>>1 -> rt = blk2*2+p; half=w&1 -> cs.
// ---------------------------------------------------------------------------
__global__ __launch_bounds__(256) void qk_proj_kernel(
    const float* __restrict__ x,
    const _Float16* __restrict__ w1p, const float* __restrict__ b1,
    const _Float16* __restrict__ w2p, const float* __restrict__ b2,
    _Float16* __restrict__ qb, _Float16* __restrict__ kb)
{
  __shared__ f32x4v red[32][64];
  const int t = threadIdx.x, w = t >> 6, l = t & 63;
  const int lr = l & 31, h = l >> 5;
  const int b = blockIdx.x >> 6;
  const int p = w >> 1, hf = w & 1;
  const int rt = (blockIdx.x & 63) * 2 + p;
  const float* xb = x + (size_t)b * 256 * 4096 + rt * 32 + lr;

  f32x16 accq = fzero16(), acck = fzero16();

  for (int cs = hf * 8; cs < hf * 8 + 8; ++cs) {
    const int c0 = cs * 16 + 4 * h;
    half8 xh, xl;
#pragma unroll
    for (int j = 0; j < 8; ++j) {
      const int c = c0 + (j & 3) + 8 * (j >> 2);
      const HiLo s = split1(xb[(size_t)c * 4096]);
      xh[j] = s.hi; xl[j] = s.lo;
    }
    const half8 w1h = *(const half8*)&w1p[(cs * 64 + l) * 8];
    const half8 w1l = *(const half8*)&w1p[8192 + (cs * 64 + l) * 8];
    const half8 w2h = *(const half8*)&w2p[(cs * 64 + l) * 8];
    const half8 w2l = *(const half8*)&w2p[8192 + (cs * 64 + l) * 8];
    accq = MFMA16(w1h, xh, accq);
    accq = MFMA16(w1h, xl, accq);
    accq = MFMA16(w1l, xh, accq);
    acck = MFMA16(w2h, xh, acck);
    acck = MFMA16(w2h, xl, acck);
    acck = MFMA16(w2l, xh, acck);
  }

#pragma unroll
  for (int i4 = 0; i4 < 4; ++i4) {
    f32x4v q4, k4;
#pragma unroll
    for (int c = 0; c < 4; ++c) { q4[c] = accq[4 * i4 + c]; k4[c] = acck[4 * i4 + c]; }
    red[w * 8 + i4][l] = q4;
    red[w * 8 + 4 + i4][l] = k4;
  }
  __syncthreads();
  if (hf == 0) {
#pragma unroll
    for (int i4 = 0; i4 < 4; ++i4) {
      const f32x4v q4 = red[(w + 1) * 8 + i4][l];
      const f32x4v k4 = red[(w + 1) * 8 + 4 + i4][l];
#pragma unroll
      for (int c = 0; c < 4; ++c) { accq[4 * i4 + c] += q4[c]; acck[4 * i4 + c] += k4[c]; }
    }
#pragma unroll
    for (int ds = 0; ds < 2; ++ds) {
      half8 phq, phk;
#pragma unroll
      for (int j = 0; j < 8; ++j) {
        const int d = 16 * ds + 4 * h + (j & 3) + 8 * (j >> 2);
        phq[j] = (_Float16)(accq[8 * ds + j] + b1[d]);
        phk[j] = (_Float16)(acck[8 * ds + j] + b2[d]);
      }
      const size_t o = ((((size_t)b * 128 + rt) * 2 + ds) * 64 + l) * 8;
      *(half8*)&qb[o] = phq;
      *(half8*)&kb[o] = phk;
    }
  }
}

// ---------------------------------------------------------------------------
// v projection with pre-split weights. Grid 4b x 128; wave -> co-tiles 2w,2w+1.
// ---------------------------------------------------------------------------
__global__ __launch_bounds__(256) void v_proj_kernel(
    const float* __restrict__ x, const _Float16* __restrict__ w3p,
    const float* __restrict__ b3, _Float16* __restrict__ vb)
{
  const int t = threadIdx.x, w = t >> 6, l = t & 63;
  const int lr = l & 31, h = l >> 5;
  const int b = blockIdx.x >> 7;
  const int nt = blockIdx.x & 127;
  const float* xb = x + (size_t)b * 256 * 4096 + nt * 32 + lr;
  const int cot0 = w * 2, cot1 = w * 2 + 1;

  f32x16 acc0 = fzero16(), acc1 = fzero16();

  for (int cs = 0; cs < 16; ++cs) {
    const int c0 = cs * 16 + 4 * h;
    half8 xh, xl;
#pragma unroll
    for (int j = 0; j < 8; ++j) {
      const int c = c0 + (j & 3) + 8 * (j >> 2);
      const HiLo s = split1(xb[(size_t)c * 4096]);
      xh[j] = s.hi; xl[j] = s.lo;
    }
    const half8 wh0 = *(const half8*)&w3p[((cot0 * 16 + cs) * 64 + l) * 8];
    const half8 wl0 = *(const half8*)&w3p[65536 + ((cot0 * 16 + cs) * 64 + l) * 8];
    const half8 wh1 = *(const half8*)&w3p[((cot1 * 16 + cs) * 64 + l) * 8];
    const half8 wl1 = *(const half8*)&w3p[65536 + ((cot1 * 16 + cs) * 64 + l) * 8];
    acc0 = MFMA16(xh, wh0, acc0);
    acc0 = MFMA16(xl, wh0, acc0);
    acc0 = MFMA16(xh, wl0, acc0);
    acc1 = MFMA16(xh, wh1, acc1);
    acc1 = MFMA16(xl, wh1, acc1);
    acc1 = MFMA16(xh, wl1, acc1);
  }

  const float bv0 = b3[cot0 * 32 + lr];
  const float bv1 = b3[cot1 * 32 + lr];
#pragma unroll
  for (int hfq = 0; hfq < 2; ++hfq) {
    half8 p0, p1;
#pragma unroll
    for (int j = 0; j < 8; ++j) {
      p0[j] = (_Float16)(acc0[8 * hfq + j] + bv0);
      p1[j] = (_Float16)(acc1[8 * hfq + j] + bv1);
    }
    const int ms = nt * 2 + hfq;
    *(half8*)&vb[((((size_t)b * 256 + ms) * 8 + cot0) * 64 + l) * 8] = p0;
    *(half8*)&vb[((((size_t)b * 256 + ms) * 8 + cot1) * 64 + l) * 8] = p1;
  }
}

// ---------------------------------------------------------------------------
// rowmax: unchanged (bitwise-identical MFMA order to attn phase A).
// ---------------------------------------------------------------------------
__global__ __launch_bounds__(256) void rowmax_kernel(
    const _Float16* __restrict__ qb, const _Float16* __restrict__ kb,
    float* __restrict__ Mrow)
{
  __shared__ float red[4][32];
  const int t = threadIdx.x, w = t >> 6, l = t & 63;
  const int b = blockIdx.x >> 7;
  const int sl = blockIdx.x & 127;
  const _Float16* qp = qb + ((((size_t)b * 128 + sl) * 2) * 64 + l) * 8;
  const half8 q0 = *(const half8*)qp;
  const half8 q1 = *(const half8*)(qp + 512);
  float vm = -3.0e38f;
  for (int mt = w * 32; mt < w * 32 + 32; ++mt) {
    const _Float16* kp = kb + ((((size_t)b * 128 + mt) * 2) * 64 + l) * 8;
    const half8 k0 = *(const half8*)kp;
    const half8 k1 = *(const half8*)(kp + 512);
    f32x16 s = fzero16();
    s = MFMA16(k0, q0, s);
    s = MFMA16(k1, q1, s);
#pragma unroll
    for (int i = 0; i < 16; ++i) vm = fmaxf(vm, s[i]);
  }
  vm = fmaxf(vm, __shfl_xor(vm, 32));
  if (l < 32) red[w][l] = vm;
  __syncthreads();
  if (t < 32) {
    float m = fmaxf(fmaxf(red[0][t], red[1][t]), fmaxf(red[2][t], red[3][t]));
    Mrow[(size_t)b * 4096 + sl * 32 + t] = m;
  }
}

// ---------------------------------------------------------------------------
// attn: block = 64 q-rows x ALL 256 couts (P computed once, shared via LDS).
// Wave w: produces S-tile (s2w=w>>1, ms2w=w&1) -> P frags to LDS; consumes
// P for cout group [w*64, w*64+64). V/K staged via global_load_lds, dbuf.
// Grid 4b x 64 = 256 blocks. LDS = 2*36KB (V+K) + 8KB (P) = 80KB.
// ---------------------------------------------------------------------------
__global__ __launch_bounds__(256) void attn_kernel(
    const _Float16* __restrict__ qb, const _Float16* __restrict__ kb,
    const _Float16* __restrict__ vb, const float* __restrict__ Mrow,
    const float* __restrict__ x, float* __restrict__ out)
{
  __shared__ __align__(16) _Float16 lds[2 * 18432 + 4096];
  __shared__ float Lred[2][2][32];
  const int PB = 2 * 18432;
  const int t = threadIdx.x, w = t >> 6, l = t & 63;
  const int lr = l & 31, h = l >> 5;
  const int b = blockIdx.x >> 6;
  const int rt64 = blockIdx.x & 63;
  const int s2w = w >> 1, ms2w = w & 1;
  const int rt32w = rt64 * 2 + s2w;

  const _Float16* qp = qb + (((size_t)b * 128 + rt32w) * 2 * 64 + l) * 8;
  const half8 qf0 = *(const half8*)qp;
  const half8 qf1 = *(const half8*)(qp + 512);
  const float Mr = Mrow[(size_t)b * 4096 + rt32w * 32 + lr];

  f32x16 acc00 = fzero16(), acc01 = fzero16();
  f32x16 acc10 = fzero16(), acc11 = fzero16();
  float Lacc = 0.f;

  // stage 36 x 1KB chunks (V: c=0..31 -> (ks=c>>3, cog=c&7); K: c=32..35)
  auto stage = [&](int tt, int buf) {
#pragma unroll
    for (int i = 0; i < 9; ++i) {
      const int c = w * 9 + i;
      const _Float16* src;
      if (c < 32) {
        src = vb + (((size_t)b * 2048 + (size_t)(tt * 4 + (c >> 3)) * 8 + (c & 7)) * 64 + l) * 8;
      } else {
        const int cc = c - 32;
        src = kb + (((size_t)b * 256 + (size_t)(tt * 2 + (cc >> 1)) * 2 + (cc & 1)) * 64 + l) * 8;
      }
      GLDS16(src, &lds[buf * 18432 + c * 512]);
    }
  };

  stage(0, 0);
  for (int t64 = 0; t64 < 64; ++t64) {
    const int cur = t64 & 1;
    const int base = cur * 18432;
    __syncthreads();                 // drains vmcnt: stage(t64) complete; prev iter LDS reads retired
    if (t64 < 63) stage(t64 + 1, cur ^ 1);

    // ---- phase A: S-tile + exp + pack -> P_lds ----
    const half8 kf0 = *(const half8*)&lds[base + (32 + ms2w * 2 + 0) * 512 + l * 8];
    const half8 kf1 = *(const half8*)&lds[base + (32 + ms2w * 2 + 1) * 512 + l * 8];
    f32x16 s = fzero16();
    s = MFMA16(kf0, qf0, s);
    s = MFMA16(kf1, qf1, s);
    float p[16];
    float ls = 0.f;
#pragma unroll
    for (int i = 0; i < 16; ++i) { p[i] = __expf(s[i] - Mr); ls += p[i]; }
    Lacc += ls;
    union { half8 v; half2v h2[4]; } u0, u1;
#pragma unroll
    for (int jj = 0; jj < 4; ++jj) {
      auto pk0 = __builtin_amdgcn_cvt_pkrtz(p[2 * jj], p[2 * jj + 1]);
      auto pk1 = __builtin_amdgcn_cvt_pkrtz(p[8 + 2 * jj], p[8 + 2 * jj + 1]);
      u0.h2[jj] = *(half2v*)&pk0;
      u1.h2[jj] = *(half2v*)&pk1;
    }
    *(half8*)&lds[PB + ((s2w * 4 + ms2w * 2 + 0) * 64 + l) * 8] = u0.v;
    *(half8*)&lds[PB + ((s2w * 4 + ms2w * 2 + 1) * 64 + l) * 8] = u1.v;

    asm volatile("s_waitcnt lgkmcnt(0)" ::: "memory");   // own P writes visible
    __builtin_amdgcn_s_barrier();                        // no vmcnt drain: stage stays in flight
    asm volatile("" ::: "memory");

    // ---- phase B: PV from shared P ----
#pragma unroll
    for (int ks = 0; ks < 4; ++ks) {
      const half8 vf0 = *(const half8*)&lds[base + (ks * 8 + 2 * w) * 512 + l * 8];
      const half8 vf1 = *(const half8*)&lds[base + (ks * 8 + 2 * w + 1) * 512 + l * 8];
      const half8 pb0 = *(const half8*)&lds[PB + ((0 + ks) * 64 + l) * 8];
      const half8 pb1 = *(const half8*)&lds[PB + ((4 + ks) * 64 + l) * 8];
      acc00 = MFMA16(vf0, pb0, acc00);
      acc01 = MFMA16(vf1, pb0, acc01);
      acc10 = MFMA16(vf0, pb1, acc10);
      acc11 = MFMA16(vf1, pb1, acc11);
    }
  }

  // ---- L reduce across wave pairs ----
  {
    const float l2 = Lacc + __shfl_xor(Lacc, 32);
    if (l < 32) Lred[s2w][ms2w][lr] = l2;
  }
  __syncthreads();
  const float invL0 = 1.0f / (Lred[0][0][lr] + Lred[0][1][lr]);
  const float invL1 = 1.0f / (Lred[1][0][lr] + Lred[1][1][lr]);

  const float* xb = x + (size_t)b * 256 * 4096;
  float* ob = out + (size_t)b * 256 * 4096;
  const int nn0 = rt64 * 64 + lr;
  const int nn1 = rt64 * 64 + 32 + lr;
#pragma unroll
  for (int reg = 0; reg < 16; ++reg) {
    const int crel = (reg & 3) + 8 * (reg >> 2) + 4 * h;
    const size_t o1 = (size_t)(w * 64 + crel) * 4096 + nn0;
    ob[o1] = acc00[reg] * invL0 + xb[o1];
    const size_t o2 = (size_t)(w * 64 + 32 + crel) * 4096 + nn0;
    ob[o2] = acc01[reg] * invL0 + xb[o2];
    const size_t o3 = (size_t)(w * 64 + crel) * 4096 + nn1;
    ob[o3] = acc10[reg] * invL1 + xb[o3];
    const size_t o4 = (size_t)(w * 64 + 32 + crel) * 4096 + nn1;
    ob[o4] = acc11[reg] * invL1 + xb[o4];
  }
}

extern "C" void kernel_launch(void* const* d_in, const int* in_sizes, int n_in,
                              void* d_out, int out_size, void* d_ws, size_t ws_size,
                              hipStream_t stream) {
  const float* x  = (const float*)d_in[0];
  const float* w1 = (const float*)d_in[1];
  const float* b1 = (const float*)d_in[2];
  const float* w2 = (const float*)d_in[3];
  const float* b2 = (const float*)d_in[4];
  const float* w3 = (const float*)d_in[5];
  const float* b3 = (const float*)d_in[6];
  float* out = (float*)d_out;

  char* ws = (char*)d_ws;
  _Float16* qb  = (_Float16*)(ws);                               // 1 MB
  _Float16* kb  = (_Float16*)(ws + (1u << 20));                  // 1 MB
  _Float16* vb  = (_Float16*)(ws + (2u << 20));                  // 8 MB
  float*    Mrow = (float*)(ws + (10u << 20));                   // 64 KB
  _Float16* w1p = (_Float16*)(ws + (10u << 20) + (64u << 10));   // 32 KB
  _Float16* w2p = (_Float16*)(ws + (10u << 20) + (96u << 10));   // 32 KB
  _Float16* w3p = (_Float16*)(ws + (10u << 20) + (128u << 10));  // 256 KB

  hipLaunchKernelGGL(wprep_kernel, dim3(9), dim3(256), 0, stream,
                     w1, w2, w3, w1p, w2p, w3p);
  hipLaunchKernelGGL(qk_proj_kernel, dim3(256), dim3(256), 0, stream,
                     x, w1p, b1, w2p, b2, qb, kb);
  hipLaunchKernelGGL(v_proj_kernel, dim3(512), dim3(256), 0, stream,
                     x, w3p, b3, vb);
  hipLaunchKernelGGL(rowmax_kernel, dim3(512), dim3(256), 0, stream, qb, kb, Mrow);
  hipLaunchKernelGGL(attn_kernel, dim3(256), dim3(256), 0, stream,
                     qb, kb, vb, Mrow, x, out);
}

// Round 5
// 103.929 us; speedup vs baseline: 3.7025x; 1.5120x over previous
//
#include <hip/hip_runtime.h>
#include <hip/hip_fp16.h>

typedef _Float16 half8 __attribute__((ext_vector_type(8)));
typedef _Float16 half2v __attribute__((ext_vector_type(2)));
typedef float f32x16 __attribute__((ext_vector_type(16)));
typedef float f32x4v __attribute__((ext_vector_type(4)));

#define MFMA16(A, B, C) __builtin_amdgcn_mfma_f32_32x32x16_f16((A), (B), (C), 0, 0, 0)

__device__ __forceinline__ f32x16 fzero16() {
  f32x16 z;
#pragma unroll
  for (int i = 0; i < 16; ++i) z[i] = 0.0f;
  return z;
}

struct HiLo { _Float16 hi, lo; };
__device__ __forceinline__ HiLo split1(float f) {
  HiLo r;
  r.hi = (_Float16)f;
  r.lo = (_Float16)(f - (float)r.hi);
  return r;
}

// ---------------------------------------------------------------------------
// wprep: pre-split weights into hi/lo fp16 MFMA-fragment layout. (unchanged)
// ---------------------------------------------------------------------------
__global__ __launch_bounds__(256) void wprep_kernel(
    const float* __restrict__ w1, const float* __restrict__ w2,
    const float* __restrict__ w3,
    _Float16* __restrict__ w1p, _Float16* __restrict__ w2p,
    _Float16* __restrict__ w3p)
{
  const int t = threadIdx.x;
  const int blk = blockIdx.x;
  if (blk < 8) {
    const int cot = blk;
    for (int e = t; e < 8192; e += 256) {
      const int j = e & 7, l = (e >> 3) & 63, cs = e >> 9;
      const int lr = l & 31, h = l >> 5;
      const int row = cot * 32 + lr;
      const int col = cs * 16 + 4 * h + (j & 3) + 8 * (j >> 2);
      const HiLo s = split1(w3[row * 256 + col]);
      const int idx = ((cot * 16 + cs) * 64 + l) * 8 + j;
      w3p[idx] = s.hi;
      w3p[65536 + idx] = s.lo;
    }
  } else {
    for (int e = t; e < 8192; e += 256) {
      const int j = e & 7, l = (e >> 3) & 63, cs = e >> 9;
      const int lr = l & 31, h = l >> 5;
      const int col = cs * 16 + 4 * h + (j & 3) + 8 * (j >> 2);
      const HiLo s1 = split1(w1[lr * 256 + col]);
      const HiLo s2 = split1(w2[lr * 256 + col]);
      const int idx = (cs * 64 + l) * 8 + j;
      w1p[idx] = s1.hi; w1p[8192 + idx] = s1.lo;
      w2p[idx] = s2.hi; w2p[8192 + idx] = s2.lo;
    }
  }
}

// ---------------------------------------------------------------------------
// q/k projection with pre-split weights; 2-way K-split + LDS reduce. (unchanged)
// ---------------------------------------------------------------------------
__global__ __launch_bounds__(256) void qk_proj_kernel(
    const float* __restrict__ x,
    const _Float16* __restrict__ w1p, const float* __restrict__ b1,
    const _Float16* __restrict__ w2p, const float* __restrict__ b2,
    _Float16* __restrict__ qb, _Float16* __restrict__ kb)
{
  __shared__ f32x4v red[32][64];
  const int t = threadIdx.x, w = t >> 6, l = t & 63;
  const int lr = l & 31, h = l >> 5;
  const int b = blockIdx.x >> 6;
  const int p = w >> 1, hf = w & 1;
  const int rt = (blockIdx.x & 63) * 2 + p;
  const float* xb = x + (size_t)b * 256 * 4096 + rt * 32 + lr;

  f32x16 accq = fzero16(), acck = fzero16();

  for (int cs = hf * 8; cs < hf * 8 + 8; ++cs) {
    const int c0 = cs * 16 + 4 * h;
    half8 xh, xl;
#pragma unroll
    for (int j = 0; j < 8; ++j) {
      const int c = c0 + (j & 3) + 8 * (j >> 2);
      const HiLo s = split1(xb[(size_t)c * 4096]);
      xh[j] = s.hi; xl[j] = s.lo;
    }
    const half8 w1h = *(const half8*)&w1p[(cs * 64 + l) * 8];
    const half8 w1l = *(const half8*)&w1p[8192 + (cs * 64 + l) * 8];
    const half8 w2h = *(const half8*)&w2p[(cs * 64 + l) * 8];
    const half8 w2l = *(const half8*)&w2p[8192 + (cs * 64 + l) * 8];
    accq = MFMA16(w1h, xh, accq);
    accq = MFMA16(w1h, xl, accq);
    accq = MFMA16(w1l, xh, accq);
    acck = MFMA16(w2h, xh, acck);
    acck = MFMA16(w2h, xl, acck);
    acck = MFMA16(w2l, xh, acck);
  }

#pragma unroll
  for (int i4 = 0; i4 < 4; ++i4) {
    f32x4v q4, k4;
#pragma unroll
    for (int c = 0; c < 4; ++c) { q4[c] = accq[4 * i4 + c]; k4[c] = acck[4 * i4 + c]; }
    red[w * 8 + i4][l] = q4;
    red[w * 8 + 4 + i4][l] = k4;
  }
  __syncthreads();
  if (hf == 0) {
#pragma unroll
    for (int i4 = 0; i4 < 4; ++i4) {
      const f32x4v q4 = red[(w + 1) * 8 + i4][l];
      const f32x4v k4 = red[(w + 1) * 8 + 4 + i4][l];
#pragma unroll
      for (int c = 0; c < 4; ++c) { accq[4 * i4 + c] += q4[c]; acck[4 * i4 + c] += k4[c]; }
    }
#pragma unroll
    for (int ds = 0; ds < 2; ++ds) {
      half8 phq, phk;
#pragma unroll
      for (int j = 0; j < 8; ++j) {
        const int d = 16 * ds + 4 * h + (j & 3) + 8 * (j >> 2);
        phq[j] = (_Float16)(accq[8 * ds + j] + b1[d]);
        phk[j] = (_Float16)(acck[8 * ds + j] + b2[d]);
      }
      const size_t o = ((((size_t)b * 128 + rt) * 2 + ds) * 64 + l) * 8;
      *(half8*)&qb[o] = phq;
      *(half8*)&kb[o] = phk;
    }
  }
}

// ---------------------------------------------------------------------------
// v projection with pre-split weights. (unchanged)
// ---------------------------------------------------------------------------
__global__ __launch_bounds__(256) void v_proj_kernel(
    const float* __restrict__ x, const _Float16* __restrict__ w3p,
    const float* __restrict__ b3, _Float16* __restrict__ vb)
{
  const int t = threadIdx.x, w = t >> 6, l = t & 63;
  const int lr = l & 31, h = l >> 5;
  const int b = blockIdx.x >> 7;
  const int nt = blockIdx.x & 127;
  const float* xb = x + (size_t)b * 256 * 4096 + nt * 32 + lr;
  const int cot0 = w * 2, cot1 = w * 2 + 1;

  f32x16 acc0 = fzero16(), acc1 = fzero16();

  for (int cs = 0; cs < 16; ++cs) {
    const int c0 = cs * 16 + 4 * h;
    half8 xh, xl;
#pragma unroll
    for (int j = 0; j < 8; ++j) {
      const int c = c0 + (j & 3) + 8 * (j >> 2);
      const HiLo s = split1(xb[(size_t)c * 4096]);
      xh[j] = s.hi; xl[j] = s.lo;
    }
    const half8 wh0 = *(const half8*)&w3p[((cot0 * 16 + cs) * 64 + l) * 8];
    const half8 wl0 = *(const half8*)&w3p[65536 + ((cot0 * 16 + cs) * 64 + l) * 8];
    const half8 wh1 = *(const half8*)&w3p[((cot1 * 16 + cs) * 64 + l) * 8];
    const half8 wl1 = *(const half8*)&w3p[65536 + ((cot1 * 16 + cs) * 64 + l) * 8];
    acc0 = MFMA16(xh, wh0, acc0);
    acc0 = MFMA16(xl, wh0, acc0);
    acc0 = MFMA16(xh, wl0, acc0);
    acc1 = MFMA16(xh, wh1, acc1);
    acc1 = MFMA16(xl, wh1, acc1);
    acc1 = MFMA16(xh, wl1, acc1);
  }

  const float bv0 = b3[cot0 * 32 + lr];
  const float bv1 = b3[cot1 * 32 + lr];
#pragma unroll
  for (int hfq = 0; hfq < 2; ++hfq) {
    half8 p0, p1;
#pragma unroll
    for (int j = 0; j < 8; ++j) {
      p0[j] = (_Float16)(acc0[8 * hfq + j] + bv0);
      p1[j] = (_Float16)(acc1[8 * hfq + j] + bv1);
    }
    const int ms = nt * 2 + hfq;
    *(half8*)&vb[((((size_t)b * 256 + ms) * 8 + cot0) * 64 + l) * 8] = p0;
    *(half8*)&vb[((((size_t)b * 256 + ms) * 8 + cot1) * 64 + l) * 8] = p1;
  }
}

// ---------------------------------------------------------------------------
// rowmax: unchanged (bitwise-identical MFMA order to attn phase A).
// ---------------------------------------------------------------------------
__global__ __launch_bounds__(256) void rowmax_kernel(
    const _Float16* __restrict__ qb, const _Float16* __restrict__ kb,
    float* __restrict__ Mrow)
{
  __shared__ float red[4][32];
  const int t = threadIdx.x, w = t >> 6, l = t & 63;
  const int b = blockIdx.x >> 7;
  const int sl = blockIdx.x & 127;
  const _Float16* qp = qb + ((((size_t)b * 128 + sl) * 2) * 64 + l) * 8;
  const half8 q0 = *(const half8*)qp;
  const half8 q1 = *(const half8*)(qp + 512);
  float vm = -3.0e38f;
  for (int mt = w * 32; mt < w * 32 + 32; ++mt) {
    const _Float16* kp = kb + ((((size_t)b * 128 + mt) * 2) * 64 + l) * 8;
    const half8 k0 = *(const half8*)kp;
    const half8 k1 = *(const half8*)(kp + 512);
    f32x16 s = fzero16();
    s = MFMA16(k0, q0, s);
    s = MFMA16(k1, q1, s);
#pragma unroll
    for (int i = 0; i < 16; ++i) vm = fmaxf(vm, s[i]);
  }
  vm = fmaxf(vm, __shfl_xor(vm, 32));
  if (l < 32) red[w][l] = vm;
  __syncthreads();
  if (t < 32) {
    float m = fmaxf(fmaxf(red[0][t], red[1][t]), fmaxf(red[2][t], red[3][t]));
    Mrow[(size_t)b * 4096 + sl * 32 + t] = m;
  }
}

// ---------------------------------------------------------------------------
// attn v2: 512 threads (8 waves = 2/SIMD), grid 4b x 64rt = 256 blocks.
// No V/K LDS staging: V/K frags loaded global->reg, double-buffered one full
// iteration ahead (L2-resident). LDS = P-exchange dbuf (16KB) + Lred only.
// Waves 0-3 produce S-tiles (s2=w>>1, ms2=w&1): QK + exp + pack -> Plds.
// All 8 waves consume: wave w owns cout32 tile w; 8 PV MFMAs/iter.
// ONE raw s_barrier per iter (P dbuf removes the WAR barrier; no vmem drain).
// ---------------------------------------------------------------------------
__global__ __launch_bounds__(512, 2) void attn_kernel(
    const _Float16* __restrict__ qb, const _Float16* __restrict__ kb,
    const _Float16* __restrict__ vb, const float* __restrict__ Mrow,
    const float* __restrict__ x, float* __restrict__ out)
{
  __shared__ __align__(16) _Float16 Plds[2][8][64][8];   // 16 KB
  __shared__ float Lred[2][2][32];
  const int t = threadIdx.x, w = t >> 6, l = t & 63;
  const int lr = l & 31, h = l >> 5;
  const int b = blockIdx.x >> 6;
  const int rt64 = blockIdx.x & 63;
  const int s2w = w >> 1, ms2w = w & 1;   // producer role (w < 4)
  const bool prod = (w < 4);

  // base pointers (lane folded in)
  const _Float16* kbase = kb + (size_t)b * 131072 + (size_t)l * 8;
  const _Float16* vbase = vb + (size_t)b * 1048576 + (size_t)l * 8;

  half8 qf0 = {}, qf1 = {};
  float Mr = 0.f, Lacc = 0.f;
  if (prod) {
    const int rt32w = rt64 * 2 + s2w;
    const _Float16* qp = qb + (((size_t)b * 128 + rt32w) * 2 * 64 + l) * 8;
    qf0 = *(const half8*)qp;
    qf1 = *(const half8*)(qp + 512);
    Mr = Mrow[(size_t)b * 4096 + rt32w * 32 + lr];
  }

  f32x16 acc0 = fzero16(), acc1 = fzero16();

  half8 vfA[4], vfB[4];
  half8 kfA0 = {}, kfA1 = {}, kfB0 = {}, kfB1 = {};
  if (prod) {
    kfA0 = *(const half8*)(kbase + ((size_t)ms2w * 2 + 0) * 512);
    kfA1 = *(const half8*)(kbase + ((size_t)ms2w * 2 + 1) * 512);
  }
#pragma unroll
  for (int ks = 0; ks < 4; ++ks)
    vfA[ks] = *(const half8*)(vbase + ((size_t)ks * 8 + w) * 512);

#define BODY(T64, VC, VN, KC0, KC1, KN0, KN1, BUF)                             \
  {                                                                            \
    const bool more = (T64) < 63;                                              \
    if (prod) {                                                                \
      f32x16 s = fzero16();                                                    \
      s = MFMA16(KC0, qf0, s);                                                 \
      s = MFMA16(KC1, qf1, s);                                                 \
      if (more) {                                                              \
        KN0 = *(const half8*)(kbase + (((size_t)((T64) + 1) * 2 + ms2w) * 2 + 0) * 512); \
        KN1 = *(const half8*)(kbase + (((size_t)((T64) + 1) * 2 + ms2w) * 2 + 1) * 512); \
      }                                                                        \
      float p[16];                                                             \
      float ls = 0.f;                                                          \
      _Pragma("unroll") for (int i = 0; i < 16; ++i) {                         \
        p[i] = __expf(s[i] - Mr); ls += p[i];                                  \
      }                                                                        \
      Lacc += ls;                                                              \
      union { half8 v; half2v h2[4]; } u0, u1;                                 \
      _Pragma("unroll") for (int jj = 0; jj < 4; ++jj) {                       \
        auto a0 = __builtin_amdgcn_cvt_pkrtz(p[2 * jj], p[2 * jj + 1]);        \
        auto a1 = __builtin_amdgcn_cvt_pkrtz(p[8 + 2 * jj], p[8 + 2 * jj + 1]);\
        u0.h2[jj] = *(half2v*)&a0;                                             \
        u1.h2[jj] = *(half2v*)&a1;                                             \
      }                                                                        \
      *(half8*)&Plds[BUF][s2w * 4 + ms2w * 2 + 0][l][0] = u0.v;                \
      *(half8*)&Plds[BUF][s2w * 4 + ms2w * 2 + 1][l][0] = u1.v;                \
    } else if ((T64) < 63) {                                                   \
      _Pragma("unroll") for (int ks = 0; ks < 4; ++ks)                         \
        VN[ks] = *(const half8*)(vbase + (((size_t)((T64) + 1) * 4 + ks) * 8 + w) * 512); \
    }                                                                          \
    asm volatile("s_waitcnt lgkmcnt(0)" ::: "memory");                         \
    __builtin_amdgcn_s_barrier();                                              \
    if (prod && more) {                                                        \
      _Pragma("unroll") for (int ks = 0; ks < 4; ++ks)                         \
        VN[ks] = *(const half8*)(vbase + (((size_t)((T64) + 1) * 4 + ks) * 8 + w) * 512); \
    }                                                                          \
    _Pragma("unroll") for (int ks = 0; ks < 4; ++ks) {                         \
      const half8 pb0 = *(const half8*)&Plds[BUF][ks][l][0];                   \
      const half8 pb1 = *(const half8*)&Plds[BUF][4 + ks][l][0];               \
      acc0 = MFMA16(VC[ks], pb0, acc0);                                        \
      acc1 = MFMA16(VC[ks], pb1, acc1);                                        \
    }                                                                          \
  }

  for (int t64 = 0; t64 < 64; t64 += 2) {
    BODY(t64,     vfA, vfB, kfA0, kfA1, kfB0, kfB1, 0)
    BODY(t64 + 1, vfB, vfA, kfB0, kfB1, kfA0, kfA1, 1)
  }
#undef BODY

  // ---- L reduce ----
  if (prod) {
    const float l2 = Lacc + __shfl_xor(Lacc, 32);
    if (l < 32) Lred[s2w][ms2w][lr] = l2;
  }
  __syncthreads();
  const float invL0 = 1.0f / (Lred[0][0][lr] + Lred[0][1][lr]);
  const float invL1 = 1.0f / (Lred[1][0][lr] + Lred[1][1][lr]);

  // ---- epilogue: normalize + residual ----
  const float* xb = x + (size_t)b * 256 * 4096;
  float* ob = out + (size_t)b * 256 * 4096;
  const int nn0 = rt64 * 64 + lr;
  const int nn1 = rt64 * 64 + 32 + lr;
#pragma unroll
  for (int reg = 0; reg < 16; ++reg) {
    const int crel = (reg & 3) + 8 * (reg >> 2) + 4 * h;
    const int cout = w * 32 + crel;
    const size_t o1 = (size_t)cout * 4096 + nn0;
    ob[o1] = acc0[reg] * invL0 + xb[o1];
    const size_t o2 = (size_t)cout * 4096 + nn1;
    ob[o2] = acc1[reg] * invL1 + xb[o2];
  }
}

extern "C" void kernel_launch(void* const* d_in, const int* in_sizes, int n_in,
                              void* d_out, int out_size, void* d_ws, size_t ws_size,
                              hipStream_t stream) {
  const float* x  = (const float*)d_in[0];
  const float* w1 = (const float*)d_in[1];
  const float* b1 = (const float*)d_in[2];
  const float* w2 = (const float*)d_in[3];
  const float* b2 = (const float*)d_in[4];
  const float* w3 = (const float*)d_in[5];
  const float* b3 = (const float*)d_in[6];
  float* out = (float*)d_out;

  char* ws = (char*)d_ws;
  _Float16* qb  = (_Float16*)(ws);                               // 1 MB
  _Float16* kb  = (_Float16*)(ws + (1u << 20));                  // 1 MB
  _Float16* vb  = (_Float16*)(ws + (2u << 20));                  // 8 MB
  float*    Mrow = (float*)(ws + (10u << 20));                   // 64 KB
  _Float16* w1p = (_Float16*)(ws + (10u << 20) + (64u << 10));   // 32 KB
  _Float16* w2p = (_Float16*)(ws + (10u << 20) + (96u << 10));   // 32 KB
  _Float16* w3p = (_Float16*)(ws + (10u << 20) + (128u << 10));  // 256 KB

  hipLaunchKernelGGL(wprep_kernel, dim3(9), dim3(256), 0, stream,
                     w1, w2, w3, w1p, w2p, w3p);
  hipLaunchKernelGGL(qk_proj_kernel, dim3(256), dim3(256), 0, stream,
                     x, w1p, b1, w2p, b2, qb, kb);
  hipLaunchKernelGGL(v_proj_kernel, dim3(512), dim3(256), 0, stream,
                     x, w3p, b3, vb);
  hipLaunchKernelGGL(rowmax_kernel, dim3(512), dim3(256), 0, stream, qb, kb, Mrow);
  hipLaunchKernelGGL(attn_kernel, dim3(256), dim3(512), 0, stream,
                     qb, kb, vb, Mrow, x, out);
}

// Round 6
// 91.263 us; speedup vs baseline: 4.2163x; 1.1388x over previous
//
#include <hip/hip_runtime.h>
#include <hip/hip_fp16.h>

typedef _Float16 half8 __attribute__((ext_vector_type(8)));
typedef _Float16 half2v __attribute__((ext_vector_type(2)));
typedef float f32x16 __attribute__((ext_vector_type(16)));
typedef float f32x4v __attribute__((ext_vector_type(4)));

#define MFMA16(A, B, C) __builtin_amdgcn_mfma_f32_32x32x16_f16((A), (B), (C), 0, 0, 0)

__device__ __forceinline__ f32x16 fzero16() {
  f32x16 z;
#pragma unroll
  for (int i = 0; i < 16; ++i) z[i] = 0.0f;
  return z;
}

struct HiLo { _Float16 hi, lo; };
__device__ __forceinline__ HiLo split1(float f) {
  HiLo r;
  r.hi = (_Float16)f;
  r.lo = (_Float16)(f - (float)r.hi);
  return r;
}

// ---------------------------------------------------------------------------
// wprep: pre-split weights into hi/lo fp16 MFMA-fragment layout. (unchanged)
// ---------------------------------------------------------------------------
__global__ __launch_bounds__(256) void wprep_kernel(
    const float* __restrict__ w1, const float* __restrict__ w2,
    const float* __restrict__ w3,
    _Float16* __restrict__ w1p, _Float16* __restrict__ w2p,
    _Float16* __restrict__ w3p)
{
  const int t = threadIdx.x;
  const int blk = blockIdx.x;
  if (blk < 8) {
    const int cot = blk;
    for (int e = t; e < 8192; e += 256) {
      const int j = e & 7, l = (e >> 3) & 63, cs = e >> 9;
      const int lr = l & 31, h = l >> 5;
      const int row = cot * 32 + lr;
      const int col = cs * 16 + 4 * h + (j & 3) + 8 * (j >> 2);
      const HiLo s = split1(w3[row * 256 + col]);
      const int idx = ((cot * 16 + cs) * 64 + l) * 8 + j;
      w3p[idx] = s.hi;
      w3p[65536 + idx] = s.lo;
    }
  } else {
    for (int e = t; e < 8192; e += 256) {
      const int j = e & 7, l = (e >> 3) & 63, cs = e >> 9;
      const int lr = l & 31, h = l >> 5;
      const int col = cs * 16 + 4 * h + (j & 3) + 8 * (j >> 2);
      const HiLo s1 = split1(w1[lr * 256 + col]);
      const HiLo s2 = split1(w2[lr * 256 + col]);
      const int idx = (cs * 64 + l) * 8 + j;
      w1p[idx] = s1.hi; w1p[8192 + idx] = s1.lo;
      w2p[idx] = s2.hi; w2p[8192 + idx] = s2.lo;
    }
  }
}

// ---------------------------------------------------------------------------
// q/k projection v2: grid 4b x 128rt = 512 blocks (2/CU). One 32-row n-tile
// per block; 4 waves do a 4-way cs (K-dim) split; 32KB LDS reduce.
// ---------------------------------------------------------------------------
__global__ __launch_bounds__(256) void qk_proj_kernel(
    const float* __restrict__ x,
    const _Float16* __restrict__ w1p, const float* __restrict__ b1,
    const _Float16* __restrict__ w2p, const float* __restrict__ b2,
    _Float16* __restrict__ qb, _Float16* __restrict__ kb)
{
  __shared__ f32x4v red[4][2][4][64];   // [wave][q/k][i4][lane], 32 KB
  const int t = threadIdx.x, w = t >> 6, l = t & 63;
  const int lr = l & 31, h = l >> 5;
  const int b = blockIdx.x >> 7;
  const int rt = blockIdx.x & 127;
  const float* xb = x + (size_t)b * 256 * 4096 + rt * 32 + lr;

  f32x16 accq = fzero16(), acck = fzero16();

  for (int cs = w * 4; cs < w * 4 + 4; ++cs) {
    const int c0 = cs * 16 + 4 * h;
    half8 xh, xl;
#pragma unroll
    for (int j = 0; j < 8; ++j) {
      const int c = c0 + (j & 3) + 8 * (j >> 2);
      const HiLo s = split1(xb[(size_t)c * 4096]);
      xh[j] = s.hi; xl[j] = s.lo;
    }
    const half8 w1h = *(const half8*)&w1p[(cs * 64 + l) * 8];
    const half8 w1l = *(const half8*)&w1p[8192 + (cs * 64 + l) * 8];
    const half8 w2h = *(const half8*)&w2p[(cs * 64 + l) * 8];
    const half8 w2l = *(const half8*)&w2p[8192 + (cs * 64 + l) * 8];
    accq = MFMA16(w1h, xh, accq);
    accq = MFMA16(w1h, xl, accq);
    accq = MFMA16(w1l, xh, accq);
    acck = MFMA16(w2h, xh, acck);
    acck = MFMA16(w2h, xl, acck);
    acck = MFMA16(w2l, xh, acck);
  }

#pragma unroll
  for (int i4 = 0; i4 < 4; ++i4) {
    f32x4v q4, k4;
#pragma unroll
    for (int c = 0; c < 4; ++c) { q4[c] = accq[4 * i4 + c]; k4[c] = acck[4 * i4 + c]; }
    red[w][0][i4][l] = q4;
    red[w][1][i4][l] = k4;
  }
  __syncthreads();
  if (w < 2) {
    _Float16* dst = (w == 0) ? qb : kb;
    const float* bias = (w == 0) ? b1 : b2;
    f32x16 tot;
#pragma unroll
    for (int i4 = 0; i4 < 4; ++i4) {
      f32x4v v = red[0][w][i4][l];
      v += red[1][w][i4][l];
      v += red[2][w][i4][l];
      v += red[3][w][i4][l];
#pragma unroll
      for (int c = 0; c < 4; ++c) tot[4 * i4 + c] = v[c];
    }
#pragma unroll
    for (int ds = 0; ds < 2; ++ds) {
      half8 ph;
#pragma unroll
      for (int j = 0; j < 8; ++j) {
        const int d = 16 * ds + 4 * h + (j & 3) + 8 * (j >> 2);
        ph[j] = (_Float16)(tot[8 * ds + j] + bias[d]);
      }
      *(half8*)&dst[((((size_t)b * 128 + rt) * 2 + ds) * 64 + l) * 8] = ph;
    }
  }
}

// ---------------------------------------------------------------------------
// v projection with pre-split weights. (unchanged)
// ---------------------------------------------------------------------------
__global__ __launch_bounds__(256) void v_proj_kernel(
    const float* __restrict__ x, const _Float16* __restrict__ w3p,
    const float* __restrict__ b3, _Float16* __restrict__ vb)
{
  const int t = threadIdx.x, w = t >> 6, l = t & 63;
  const int lr = l & 31, h = l >> 5;
  const int b = blockIdx.x >> 7;
  const int nt = blockIdx.x & 127;
  const float* xb = x + (size_t)b * 256 * 4096 + nt * 32 + lr;
  const int cot0 = w * 2, cot1 = w * 2 + 1;

  f32x16 acc0 = fzero16(), acc1 = fzero16();

  for (int cs = 0; cs < 16; ++cs) {
    const int c0 = cs * 16 + 4 * h;
    half8 xh, xl;
#pragma unroll
    for (int j = 0; j < 8; ++j) {
      const int c = c0 + (j & 3) + 8 * (j >> 2);
      const HiLo s = split1(xb[(size_t)c * 4096]);
      xh[j] = s.hi; xl[j] = s.lo;
    }
    const half8 wh0 = *(const half8*)&w3p[((cot0 * 16 + cs) * 64 + l) * 8];
    const half8 wl0 = *(const half8*)&w3p[65536 + ((cot0 * 16 + cs) * 64 + l) * 8];
    const half8 wh1 = *(const half8*)&w3p[((cot1 * 16 + cs) * 64 + l) * 8];
    const half8 wl1 = *(const half8*)&w3p[65536 + ((cot1 * 16 + cs) * 64 + l) * 8];
    acc0 = MFMA16(xh, wh0, acc0);
    acc0 = MFMA16(xl, wh0, acc0);
    acc0 = MFMA16(xh, wl0, acc0);
    acc1 = MFMA16(xh, wh1, acc1);
    acc1 = MFMA16(xl, wh1, acc1);
    acc1 = MFMA16(xh, wl1, acc1);
  }

  const float bv0 = b3[cot0 * 32 + lr];
  const float bv1 = b3[cot1 * 32 + lr];
#pragma unroll
  for (int hfq = 0; hfq < 2; ++hfq) {
    half8 p0, p1;
#pragma unroll
    for (int j = 0; j < 8; ++j) {
      p0[j] = (_Float16)(acc0[8 * hfq + j] + bv0);
      p1[j] = (_Float16)(acc1[8 * hfq + j] + bv1);
    }
    const int ms = nt * 2 + hfq;
    *(half8*)&vb[((((size_t)b * 256 + ms) * 8 + cot0) * 64 + l) * 8] = p0;
    *(half8*)&vb[((((size_t)b * 256 + ms) * 8 + cot1) * 64 + l) * 8] = p1;
  }
}

// ---------------------------------------------------------------------------
// rowmax v2: 512 thr / 8 waves, wave w covers mt in [16w, 16w+16).
// Bitwise-identical MFMA order to attn QK.
// ---------------------------------------------------------------------------
__global__ __launch_bounds__(512) void rowmax_kernel(
    const _Float16* __restrict__ qb, const _Float16* __restrict__ kb,
    float* __restrict__ Mrow)
{
  __shared__ float red[8][32];
  const int t = threadIdx.x, w = t >> 6, l = t & 63;
  const int b = blockIdx.x >> 7;
  const int sl = blockIdx.x & 127;
  const _Float16* qp = qb + ((((size_t)b * 128 + sl) * 2) * 64 + l) * 8;
  const half8 q0 = *(const half8*)qp;
  const half8 q1 = *(const half8*)(qp + 512);
  float vm = -3.0e38f;
  for (int mt = w * 16; mt < w * 16 + 16; ++mt) {
    const _Float16* kp = kb + ((((size_t)b * 128 + mt) * 2) * 64 + l) * 8;
    const half8 k0 = *(const half8*)kp;
    const half8 k1 = *(const half8*)(kp + 512);
    f32x16 s = fzero16();
    s = MFMA16(k0, q0, s);
    s = MFMA16(k1, q1, s);
#pragma unroll
    for (int i = 0; i < 16; ++i) vm = fmaxf(vm, s[i]);
  }
  vm = fmaxf(vm, __shfl_xor(vm, 32));
  if (l < 32) red[w][l] = vm;
  __syncthreads();
  if (t < 32) {
    float m = red[0][t];
#pragma unroll
    for (int ww = 1; ww < 8; ++ww) m = fmaxf(m, red[ww][t]);
    Mrow[(size_t)b * 4096 + sl * 32 + t] = m;
  }
}

// ---------------------------------------------------------------------------
// attn v3: pipelined P production. 512 thr (8 waves), grid 4b x 64rt = 256.
// During iter t, ALL waves do PV from Plds[t&1] while producer waves (0-3)
// concurrently compute S(t+1) -> Plds[(t+1)&1] (QK MFMA + exp VALU overlap
// the PV MFMAs). One raw s_barrier per iter, no vmem drains.
// ---------------------------------------------------------------------------
__global__ __launch_bounds__(512, 2) void attn_kernel(
    const _Float16* __restrict__ qb, const _Float16* __restrict__ kb,
    const _Float16* __restrict__ vb, const float* __restrict__ Mrow,
    const float* __restrict__ x, float* __restrict__ out)
{
  __shared__ __align__(16) _Float16 Plds[2][8][64][8];   // 16 KB
  __shared__ float Lred[2][2][32];
  const int t = threadIdx.x, w = t >> 6, l = t & 63;
  const int lr = l & 31, h = l >> 5;
  const int b = blockIdx.x >> 6;
  const int rt64 = blockIdx.x & 63;
  const int s2w = w >> 1, ms2w = w & 1;   // producer role (w < 4)
  const bool prod = (w < 4);

  const _Float16* kbase = kb + (size_t)b * 131072 + (size_t)l * 8;
  const _Float16* vbase = vb + (size_t)b * 1048576 + (size_t)l * 8;

#define KLOAD(tt, ds) (*(const half8*)(kbase + ((size_t)(2 * (tt) + ms2w) * 2 + (ds)) * 512))
#define VLOAD(tt, ks) (*(const half8*)(vbase + (((size_t)(tt) * 4 + (ks)) * 8 + w) * 512))

  half8 qf0 = {}, qf1 = {};
  float Mr = 0.f, Lacc = 0.f;
  if (prod) {
    const int rt32w = rt64 * 2 + s2w;
    const _Float16* qp = qb + (((size_t)b * 128 + rt32w) * 2 * 64 + l) * 8;
    qf0 = *(const half8*)qp;
    qf1 = *(const half8*)(qp + 512);
    Mr = Mrow[(size_t)b * 4096 + rt32w * 32 + lr];
  }

  f32x16 acc0 = fzero16(), acc1 = fzero16();
  half8 vfA[4], vfB[4];
  half8 kfA0 = {}, kfA1 = {}, kfB0 = {}, kfB1 = {};

#define EXPPACK(S, BUF)                                                        \
  {                                                                            \
    float p[16];                                                               \
    float ls = 0.f;                                                            \
    _Pragma("unroll") for (int i = 0; i < 16; ++i) {                           \
      p[i] = __expf((S)[i] - Mr); ls += p[i];                                  \
    }                                                                          \
    Lacc += ls;                                                                \
    union { half8 v; half2v h2[4]; } u0, u1;                                   \
    _Pragma("unroll") for (int jj = 0; jj < 4; ++jj) {                         \
      auto a0 = __builtin_amdgcn_cvt_pkrtz(p[2 * jj], p[2 * jj + 1]);          \
      auto a1 = __builtin_amdgcn_cvt_pkrtz(p[8 + 2 * jj], p[8 + 2 * jj + 1]);  \
      u0.h2[jj] = *(half2v*)&a0;                                               \
      u1.h2[jj] = *(half2v*)&a1;                                               \
    }                                                                          \
    *(half8*)&Plds[BUF][s2w * 4 + ms2w * 2 + 0][l][0] = u0.v;                  \
    *(half8*)&Plds[BUF][s2w * 4 + ms2w * 2 + 1][l][0] = u1.v;                  \
  }

  // ---- prologue: V(0); producers S(0)->Plds[0], prefetch K(1) ----
#pragma unroll
  for (int ks = 0; ks < 4; ++ks) vfA[ks] = VLOAD(0, ks);
  if (prod) {
    const half8 k00 = KLOAD(0, 0);
    const half8 k01 = KLOAD(0, 1);
    f32x16 s0 = fzero16();
    s0 = MFMA16(k00, qf0, s0);
    s0 = MFMA16(k01, qf1, s0);
    kfA0 = KLOAD(1, 0);
    kfA1 = KLOAD(1, 1);
    EXPPACK(s0, 0)
  }
  asm volatile("s_waitcnt lgkmcnt(0)" ::: "memory");
  __builtin_amdgcn_s_barrier();

#define BODY(T, VC, VN, KC0, KC1, KN0, KN1, BUF)                               \
  {                                                                            \
    half8 pb0[4], pb1[4];                                                      \
    _Pragma("unroll") for (int ks = 0; ks < 4; ++ks) {                         \
      pb0[ks] = *(const half8*)&Plds[BUF][ks][l][0];                           \
      pb1[ks] = *(const half8*)&Plds[BUF][4 + ks][l][0];                       \
    }                                                                          \
    const bool more = (T) < 63;                                                \
    f32x16 s;                                                                  \
    if (prod && more) {                                                        \
      s = fzero16();                                                           \
      s = MFMA16(KC0, qf0, s);                                                 \
      s = MFMA16(KC1, qf1, s);                                                 \
      if ((T) < 62) { KN0 = KLOAD((T) + 2, 0); KN1 = KLOAD((T) + 2, 1); }      \
    }                                                                          \
    _Pragma("unroll") for (int ks = 0; ks < 4; ++ks) {                         \
      acc0 = MFMA16(VC[ks], pb0[ks], acc0);                                    \
      acc1 = MFMA16(VC[ks], pb1[ks], acc1);                                    \
    }                                                                          \
    if (more) {                                                                \
      _Pragma("unroll") for (int ks = 0; ks < 4; ++ks)                         \
        VN[ks] = VLOAD((T) + 1, ks);                                           \
    }                                                                          \
    if (prod && more) { EXPPACK(s, (BUF) ^ 1) }                                \
    asm volatile("s_waitcnt lgkmcnt(0)" ::: "memory");                         \
    __builtin_amdgcn_s_barrier();                                              \
  }

  for (int t64 = 0; t64 < 64; t64 += 2) {
    BODY(t64,     vfA, vfB, kfA0, kfA1, kfB0, kfB1, 0)
    BODY(t64 + 1, vfB, vfA, kfB0, kfB1, kfA0, kfA1, 1)
  }
#undef BODY
#undef EXPPACK
#undef KLOAD
#undef VLOAD

  // ---- L reduce ----
  if (prod) {
    const float l2 = Lacc + __shfl_xor(Lacc, 32);
    if (l < 32) Lred[s2w][ms2w][lr] = l2;
  }
  __syncthreads();
  const float invL0 = 1.0f / (Lred[0][0][lr] + Lred[0][1][lr]);
  const float invL1 = 1.0f / (Lred[1][0][lr] + Lred[1][1][lr]);

  // ---- epilogue: normalize + residual ----
  const float* xb = x + (size_t)b * 256 * 4096;
  float* ob = out + (size_t)b * 256 * 4096;
  const int nn0 = rt64 * 64 + lr;
  const int nn1 = rt64 * 64 + 32 + lr;
#pragma unroll
  for (int reg = 0; reg < 16; ++reg) {
    const int crel = (reg & 3) + 8 * (reg >> 2) + 4 * h;
    const int cout = w * 32 + crel;
    const size_t o1 = (size_t)cout * 4096 + nn0;
    ob[o1] = acc0[reg] * invL0 + xb[o1];
    const size_t o2 = (size_t)cout * 4096 + nn1;
    ob[o2] = acc1[reg] * invL1 + xb[o2];
  }
}

extern "C" void kernel_launch(void* const* d_in, const int* in_sizes, int n_in,
                              void* d_out, int out_size, void* d_ws, size_t ws_size,
                              hipStream_t stream) {
  const float* x  = (const float*)d_in[0];
  const float* w1 = (const float*)d_in[1];
  const float* b1 = (const float*)d_in[2];
  const float* w2 = (const float*)d_in[3];
  const float* b2 = (const float*)d_in[4];
  const float* w3 = (const float*)d_in[5];
  const float* b3 = (const float*)d_in[6];
  float* out = (float*)d_out;

  char* ws = (char*)d_ws;
  _Float16* qb  = (_Float16*)(ws);                               // 1 MB
  _Float16* kb  = (_Float16*)(ws + (1u << 20));                  // 1 MB
  _Float16* vb  = (_Float16*)(ws + (2u << 20));                  // 8 MB
  float*    Mrow = (float*)(ws + (10u << 20));                   // 64 KB
  _Float16* w1p = (_Float16*)(ws + (10u << 20) + (64u << 10));   // 32 KB
  _Float16* w2p = (_Float16*)(ws + (10u << 20) + (96u << 10));   // 32 KB
  _Float16* w3p = (_Float16*)(ws + (10u << 20) + (128u << 10));  // 256 KB

  hipLaunchKernelGGL(wprep_kernel, dim3(9), dim3(256), 0, stream,
                     w1, w2, w3, w1p, w2p, w3p);
  hipLaunchKernelGGL(qk_proj_kernel, dim3(512), dim3(256), 0, stream,
                     x, w1p, b1, w2p, b2, qb, kb);
  hipLaunchKernelGGL(v_proj_kernel, dim3(512), dim3(256), 0, stream,
                     x, w3p, b3, vb);
  hipLaunchKernelGGL(rowmax_kernel, dim3(512), dim3(512), 0, stream, qb, kb, Mrow);
  hipLaunchKernelGGL(attn_kernel, dim3(256), dim3(512), 0, stream,
                     qb, kb, vb, Mrow, x, out);
}